// Round 1
// baseline (130.034 us; speedup 1.0000x reference)
//
#include <hip/hip_runtime.h>
#include <hip/hip_bf16.h>
#include <stdint.h>

// MultiHeadAttention pipeline for MI355X (gfx950), all-MFMA bf16.
// Key insight: reference's "softmax" divides e[s,t] by D[t] (row-sum of row t,
// due to axis misalignment in the broadcast), so D folds into V before PV.
#define NB 4
#define NH 16
#define HDIM 64
#define NS 1024
#define NE 1024

typedef __bf16 bf16x8 __attribute__((ext_vector_type(8)));
typedef float f32x4 __attribute__((ext_vector_type(4)));
typedef unsigned int uint4v __attribute__((ext_vector_type(4)));
typedef unsigned int uint2v __attribute__((ext_vector_type(2)));
typedef unsigned short u16;

__device__ __forceinline__ u16 f2bf(float f) {
  unsigned u = __float_as_uint(f);
  u = (u + 0x7fffu + ((u >> 16) & 1u)) >> 16;  // RNE
  return (u16)u;
}
__device__ __forceinline__ float bf2f(u16 h) {
  return __uint_as_float(((unsigned)h) << 16);
}
__device__ __forceinline__ f32x4 mfma16(bf16x8 a, bf16x8 b, f32x4 c) {
  return __builtin_amdgcn_mfma_f32_16x16x32_bf16(a, b, c, 0, 0, 0);
}
__device__ __forceinline__ bf16x8 ld_bf8(const u16* p) {
  return __builtin_bit_cast(bf16x8, *(const uint4v*)p);
}

// ---------------------------------------------------------------------------
// Kernel 1: per-head projections q/k/v. out[d,s] = sum_e W[h][d][e] x[b][h*64+e][s]
// Writes qT/kT as [bh][s][d] (d contiguous) and v as [bh][d][s] (s contiguous).
// grid (S/256, B*H, 3), 256 threads (4 waves), each wave a 64x64 output tile.
__global__ __launch_bounds__(256) void proj_kernel(
    const float* __restrict__ q_in, const float* __restrict__ k_in,
    const float* __restrict__ v_in, const float* __restrict__ Wq,
    const float* __restrict__ Wk, const float* __restrict__ Wv,
    u16* __restrict__ qT, u16* __restrict__ kT, u16* __restrict__ vv)
{
  const int which = blockIdx.z;
  const int bh = blockIdx.y;
  const int b = bh >> 4, h = bh & 15;
  const int s0 = blockIdx.x * 256;
  const int tid = threadIdx.x;
  const int w = tid >> 6, l = tid & 63, lr = l & 15, lg = l >> 4;

  const float* x = (which == 0) ? q_in : (which == 1) ? k_in : v_in;
  const float* W = ((which == 0) ? Wq : (which == 1) ? Wk : Wv) + h * 4096;

  __shared__ alignas(16) u16 xT[256][72];  // [s][e], pad 72 (144B rows, 16B aligned)
  __shared__ alignas(16) u16 Wl[64][72];   // [d][e]

  // stage W 64x64 fp32 -> bf16
  #pragma unroll
  for (int j = 0; j < 4; ++j) {
    int i = tid * 4 + j;        // chunk 0..1023 (4 floats each)
    int d = i >> 4;
    int e0 = (i & 15) * 4;
    float4 f = *(const float4*)(W + d * 64 + e0);
    uint2v p;
    p[0] = (unsigned)f2bf(f.x) | ((unsigned)f2bf(f.y) << 16);
    p[1] = (unsigned)f2bf(f.z) | ((unsigned)f2bf(f.w) << 16);
    *(uint2v*)&Wl[d][e0] = p;
  }
  // stage x column s = s0+tid, transposed into xT[s][e] (coalesced global reads)
  {
    const float* xp = x + ((size_t)b * NE + h * 64) * NS + s0 + tid;
    #pragma unroll
    for (int j = 0; j < 8; ++j) {
      uint4v pk;
      #pragma unroll
      for (int q = 0; q < 4; ++q) {
        float f0 = xp[(size_t)(j * 8 + q * 2) * NS];
        float f1 = xp[(size_t)(j * 8 + q * 2 + 1) * NS];
        pk[q] = (unsigned)f2bf(f0) | ((unsigned)f2bf(f1) << 16);
      }
      *(uint4v*)&xT[tid][j * 8] = pk;
    }
  }
  __syncthreads();

  // A = W (m=d, k=e), B = x (k=e, n=s); wave w covers s cols w*64..w*64+63
  bf16x8 af[4][2];
  #pragma unroll
  for (int mt = 0; mt < 4; ++mt) {
    af[mt][0] = ld_bf8(&Wl[mt * 16 + lr][lg * 8]);
    af[mt][1] = ld_bf8(&Wl[mt * 16 + lr][32 + lg * 8]);
  }
  f32x4 acc[4][4] = {};
  #pragma unroll
  for (int nt = 0; nt < 4; ++nt) {
    bf16x8 b0 = ld_bf8(&xT[w * 64 + nt * 16 + lr][lg * 8]);
    bf16x8 b1 = ld_bf8(&xT[w * 64 + nt * 16 + lr][32 + lg * 8]);
    #pragma unroll
    for (int mt = 0; mt < 4; ++mt) {
      acc[mt][nt] = mfma16(af[mt][0], b0, acc[mt][nt]);
      acc[mt][nt] = mfma16(af[mt][1], b1, acc[mt][nt]);
    }
  }

  if (which < 2) {
    // qT/kT layout [bh][s][d]: per (mt,nt) the 4 regs are consecutive d -> 8B store
    u16* o = ((which == 0) ? qT : kT) + (size_t)bh * NS * 64;
    #pragma unroll
    for (int mt = 0; mt < 4; ++mt)
      #pragma unroll
      for (int nt = 0; nt < 4; ++nt) {
        int s = s0 + w * 64 + nt * 16 + lr;
        int d = mt * 16 + lg * 4;
        uint2v p;
        p[0] = (unsigned)f2bf(acc[mt][nt][0]) | ((unsigned)f2bf(acc[mt][nt][1]) << 16);
        p[1] = (unsigned)f2bf(acc[mt][nt][2]) | ((unsigned)f2bf(acc[mt][nt][3]) << 16);
        *(uint2v*)(o + (size_t)s * 64 + d) = p;
      }
  } else {
    // v layout [bh][d][s]: 2B stores, 16 lanes contiguous in s
    u16* o = vv + (size_t)bh * 64 * NS;
    #pragma unroll
    for (int mt = 0; mt < 4; ++mt)
      #pragma unroll
      for (int nt = 0; nt < 4; ++nt)
        #pragma unroll
        for (int jr = 0; jr < 4; ++jr) {
          int d = mt * 16 + lg * 4 + jr;
          int s = s0 + w * 64 + nt * 16 + lr;
          o[(size_t)d * NS + s] = f2bf(acc[mt][nt][jr]);
        }
  }
}

// ---------------------------------------------------------------------------
// Kernel 2: Wf fp32 -> bf16
__global__ __launch_bounds__(256) void wfconv(const float* __restrict__ Wf,
                                              u16* __restrict__ Wf16) {
  int i = blockIdx.x * 256 + threadIdx.x;  // 0..262143, 4 elems each
  float4 f = ((const float4*)Wf)[i];
  uint2v p;
  p[0] = (unsigned)f2bf(f.x) | ((unsigned)f2bf(f.y) << 16);
  p[1] = (unsigned)f2bf(f.z) | ((unsigned)f2bf(f.w) << 16);
  ((uint2v*)Wf16)[i] = p;
}

// ---------------------------------------------------------------------------
// Kernel 3: row-sum pass. D[s] = sum_{t<=s} exp(q.k/8); then fold 1/D into v's
// columns (v'[d,j] = v[d,j]/D[j]). One block per (bh, 64-row tile); 4 waves,
// each wave owns 16 query rows as MFMA m-rows.
__global__ __launch_bounds__(256) void denom_kernel(
    const u16* __restrict__ qT, const u16* __restrict__ kT,
    u16* __restrict__ vv)
{
  const int bh = blockIdx.y;
  const int i0 = blockIdx.x * 64;
  const int tid = threadIdx.x, w = tid >> 6, l = tid & 63, lr = l & 15, lg = l >> 4;
  __shared__ alignas(16) u16 klds[64][72];
  __shared__ float Dsh[64];
  const u16* qb = qT + (size_t)bh * NS * 64;
  const u16* kb = kT + (size_t)bh * NS * 64;
  const int ib = i0 + w * 16;
  bf16x8 aq0 = ld_bf8(qb + (size_t)(ib + lr) * 64 + lg * 8);
  bf16x8 aq1 = ld_bf8(qb + (size_t)(ib + lr) * 64 + 32 + lg * 8);
  f32x4 den = {0.f, 0.f, 0.f, 0.f};
  const int ntt = blockIdx.x + 1;  // causal: t-tiles 0..i0/64
  for (int tt = 0; tt < ntt; ++tt) {
    int t0 = tt * 64;
    __syncthreads();
    #pragma unroll
    for (int c0 = 0; c0 < 512; c0 += 256) {
      int c = c0 + tid, row = c >> 3, cx = c & 7;
      *(uint4v*)&klds[row][cx * 8] = *(const uint4v*)(kb + (size_t)(t0 + row) * 64 + cx * 8);
    }
    __syncthreads();
    #pragma unroll
    for (int nt = 0; nt < 4; ++nt) {
      bf16x8 b0 = ld_bf8(&klds[nt * 16 + lr][lg * 8]);
      bf16x8 b1 = ld_bf8(&klds[nt * 16 + lr][32 + lg * 8]);
      f32x4 z = {0.f, 0.f, 0.f, 0.f};
      f32x4 sc = mfma16(aq0, b0, z);
      sc = mfma16(aq1, b1, sc);
      #pragma unroll
      for (int jr = 0; jr < 4; ++jr) {
        int gi = ib + lg * 4 + jr;
        int gt = t0 + nt * 16 + lr;
        den[jr] += (gt <= gi) ? __expf(sc[jr] * 0.125f) : 0.f;
      }
    }
  }
  // reduce across the 16 lanes of each row-group (cols), share via LDS
  #pragma unroll
  for (int jr = 0; jr < 4; ++jr) {
    float d = den[jr];
    d += __shfl_xor(d, 1);
    d += __shfl_xor(d, 2);
    d += __shfl_xor(d, 4);
    d += __shfl_xor(d, 8);
    if (lr == 0) Dsh[w * 16 + lg * 4 + jr] = d;
  }
  __syncthreads();
  // scale v columns s = i0..i0+63 by 1/D[s]
  float rD = 1.0f / Dsh[l];
  u16* vp = vv + (size_t)bh * 64 * NS + i0 + l;
  #pragma unroll
  for (int d = 0; d < 16; ++d) {
    size_t off = (size_t)(d * 4 + w) * NS;
    vp[off] = f2bf(bf2f(vp[off]) * rD);
  }
}

// ---------------------------------------------------------------------------
// Kernel 4: attention. out_hT[i][d] = sum_{j<=i} exp(q_i.k_j/8) * v'[d][j].
// P goes through a per-wave LDS tile to re-fragment D-layout -> A-layout.
// Output written as X[b][s][h*64+d] (f contiguous) for the final GEMM.
__global__ __launch_bounds__(256) void attn_kernel(
    const u16* __restrict__ qT, const u16* __restrict__ kT,
    const u16* __restrict__ vv, u16* __restrict__ X)
{
  const int bh = blockIdx.y;
  const int b = bh >> 4, h = bh & 15;
  const int i0 = blockIdx.x * 64;
  const int tid = threadIdx.x, w = tid >> 6, l = tid & 63, lr = l & 15, lg = l >> 4;
  __shared__ alignas(16) u16 klds[64][72];
  __shared__ alignas(16) u16 vlds[64][72];
  __shared__ alignas(16) u16 plds[4][16][72];
  const u16* qb = qT + (size_t)bh * NS * 64;
  const u16* kb = kT + (size_t)bh * NS * 64;
  const u16* vb = vv + (size_t)bh * 64 * NS;
  const int ib = i0 + w * 16;
  bf16x8 aq0 = ld_bf8(qb + (size_t)(ib + lr) * 64 + lg * 8);
  bf16x8 aq1 = ld_bf8(qb + (size_t)(ib + lr) * 64 + 32 + lg * 8);
  f32x4 acc[4] = {};
  const int ntt = blockIdx.x + 1;
  for (int tt = 0; tt < ntt; ++tt) {
    int t0 = tt * 64;
    __syncthreads();
    #pragma unroll
    for (int c0 = 0; c0 < 1024; c0 += 256) {
      int c = c0 + tid;
      int row = (c >> 3) & 63, cx = c & 7;
      if (c < 512)
        *(uint4v*)&klds[row][cx * 8] = *(const uint4v*)(kb + (size_t)(t0 + row) * 64 + cx * 8);
      else
        *(uint4v*)&vlds[row][cx * 8] = *(const uint4v*)(vb + (size_t)row * NS + t0 + cx * 8);
    }
    __syncthreads();
    // QK^T: scores for 16 rows x 64 cols per wave, exp + causal mask -> plds
    #pragma unroll
    for (int nt = 0; nt < 4; ++nt) {
      bf16x8 b0 = ld_bf8(&klds[nt * 16 + lr][lg * 8]);
      bf16x8 b1 = ld_bf8(&klds[nt * 16 + lr][32 + lg * 8]);
      f32x4 z = {0.f, 0.f, 0.f, 0.f};
      f32x4 sc = mfma16(aq0, b0, z);
      sc = mfma16(aq1, b1, sc);
      #pragma unroll
      for (int jr = 0; jr < 4; ++jr) {
        int gi = ib + lg * 4 + jr;
        int gt = t0 + nt * 16 + lr;
        float ev = (gt <= gi) ? __expf(sc[jr] * 0.125f) : 0.f;
        plds[w][lg * 4 + jr][nt * 16 + lr] = f2bf(ev);
      }
    }
    // PV: A = P (m=i, k=j), B = v' (k=j, n=d)
    bf16x8 ap0 = ld_bf8(&plds[w][lr][lg * 8]);
    bf16x8 ap1 = ld_bf8(&plds[w][lr][32 + lg * 8]);
    #pragma unroll
    for (int nt = 0; nt < 4; ++nt) {
      bf16x8 v0 = ld_bf8(&vlds[nt * 16 + lr][lg * 8]);
      bf16x8 v1 = ld_bf8(&vlds[nt * 16 + lr][32 + lg * 8]);
      acc[nt] = mfma16(ap0, v0, acc[nt]);
      acc[nt] = mfma16(ap1, v1, acc[nt]);
    }
  }
  u16* Xp = X + (size_t)b * NS * NE + h * 64;
  #pragma unroll
  for (int nt = 0; nt < 4; ++nt)
    #pragma unroll
    for (int jr = 0; jr < 4; ++jr) {
      int s = ib + lg * 4 + jr;
      Xp[(size_t)s * NE + nt * 16 + lr] = f2bf(acc[nt][jr]);
    }
}

// ---------------------------------------------------------------------------
// Kernel 5: out[b][e][s] = sum_f Wf[e][f] * X[b][s][f]. 128x128 tile, 4 waves,
// each wave 64x64, BK=64, fp32 output.
__global__ __launch_bounds__(256) void final_gemm(
    const u16* __restrict__ Wf16, const u16* __restrict__ X,
    float* __restrict__ out)
{
  const int b = blockIdx.z;
  const int e0 = blockIdx.y * 128;
  const int s0 = blockIdx.x * 128;
  const int tid = threadIdx.x, w = tid >> 6, l = tid & 63, lr = l & 15, lg = l >> 4;
  const int wm = (w >> 1) * 64, wn = (w & 1) * 64;
  __shared__ alignas(16) u16 Alds[128][72];  // Wf rows (m=e, k=f)
  __shared__ alignas(16) u16 Blds[128][72];  // X rows (n=s, k=f)
  const u16* Xb = X + (size_t)b * NS * NE;
  f32x4 acc[4][4] = {};
  for (int k0 = 0; k0 < NE; k0 += 64) {
    __syncthreads();
    #pragma unroll
    for (int c0 = 0; c0 < 2048; c0 += 256) {
      int c = c0 + tid;
      int cc = c & 1023;
      int row = cc >> 3, cx = cc & 7;
      if (c < 1024)
        *(uint4v*)&Alds[row][cx * 8] =
            *(const uint4v*)(Wf16 + (size_t)(e0 + row) * NE + k0 + cx * 8);
      else
        *(uint4v*)&Blds[row][cx * 8] =
            *(const uint4v*)(Xb + (size_t)(s0 + row) * NE + k0 + cx * 8);
    }
    __syncthreads();
    #pragma unroll
    for (int kk = 0; kk < 2; ++kk) {
      bf16x8 a[4], bb[4];
      #pragma unroll
      for (int mt = 0; mt < 4; ++mt)
        a[mt] = ld_bf8(&Alds[wm + mt * 16 + lr][kk * 32 + lg * 8]);
      #pragma unroll
      for (int nt = 0; nt < 4; ++nt)
        bb[nt] = ld_bf8(&Blds[wn + nt * 16 + lr][kk * 32 + lg * 8]);
      #pragma unroll
      for (int mt = 0; mt < 4; ++mt)
        #pragma unroll
        for (int nt = 0; nt < 4; ++nt)
          acc[mt][nt] = mfma16(a[mt], bb[nt], acc[mt][nt]);
    }
  }
  #pragma unroll
  for (int mt = 0; mt < 4; ++mt)
    #pragma unroll
    for (int nt = 0; nt < 4; ++nt) {
      int e = e0 + wm + mt * 16 + lg * 4;
      int s = s0 + wn + nt * 16 + lr;
      float* op = out + ((size_t)b * NE + e) * NS + s;
      op[0] = acc[mt][nt][0];
      op[NS] = acc[mt][nt][1];
      op[2 * NS] = acc[mt][nt][2];
      op[3 * NS] = acc[mt][nt][3];
    }
}

// ---------------------------------------------------------------------------
extern "C" void kernel_launch(void* const* d_in, const int* in_sizes, int n_in,
                              void* d_out, int out_size, void* d_ws, size_t ws_size,
                              hipStream_t stream) {
  (void)in_sizes; (void)n_in; (void)out_size; (void)ws_size;
  const float* q_in = (const float*)d_in[0];
  const float* k_in = (const float*)d_in[1];
  const float* v_in = (const float*)d_in[2];
  // d_in[3] = mask: deterministic causal tril, implemented analytically
  const float* Wq = (const float*)d_in[4];
  const float* Wk = (const float*)d_in[5];
  const float* Wv = (const float*)d_in[6];
  const float* Wf = (const float*)d_in[7];

  u16* qT = (u16*)d_ws;                              // [bh][s][d]   8 MiB
  u16* kT = qT + (size_t)NB * NH * NS * HDIM;        // [bh][s][d]   8 MiB
  u16* vv = kT + (size_t)NB * NH * NS * HDIM;        // [bh][d][s]   8 MiB
  u16* X  = vv + (size_t)NB * NH * HDIM * NS;        // [b][s][f]    8 MiB
  u16* Wf16 = X + (size_t)NB * NS * NE;              // [e][f]       2 MiB

  proj_kernel<<<dim3(4, 64, 3), 256, 0, stream>>>(q_in, k_in, v_in, Wq, Wk, Wv, qT, kT, vv);
  wfconv<<<dim3(1024), 256, 0, stream>>>(Wf, Wf16);
  denom_kernel<<<dim3(16, 64), 256, 0, stream>>>(qT, kT, vv);
  attn_kernel<<<dim3(16, 64), 256, 0, stream>>>(qT, kT, vv, X);
  final_gemm<<<dim3(8, 8, 4), 256, 0, stream>>>(Wf16, X, (float*)d_out);
}

// Round 2
// 85.644 us; speedup vs baseline: 1.5183x; 1.5183x over previous
//
#include <hip/hip_runtime.h>
#include <hip/hip_bf16.h>
#include <stdint.h>

// MultiHeadAttention pipeline for MI355X (gfx950), all-MFMA bf16.
// Reference's "softmax" divides e[s,t] by D[t] (row-sum of row t), so D folds
// into V before PV. Round 2: swapped QK^T (A=K,B=Q) for packed P writes and
// in-lane denom rowsums; KBLK=128; heavy-first causal schedule; reg-prefetch
// double buffering; 8-wave final GEMM; 1/8 scale folded into Wq.
#define NB 4
#define NH 16
#define HDIM 64
#define NS 1024
#define NE 1024

typedef __bf16 bf16x8 __attribute__((ext_vector_type(8)));
typedef float f32x4 __attribute__((ext_vector_type(4)));
typedef unsigned int uint4v __attribute__((ext_vector_type(4)));
typedef unsigned int uint2v __attribute__((ext_vector_type(2)));
typedef unsigned short u16;

__device__ __forceinline__ u16 f2bf(float f) {
  unsigned u = __float_as_uint(f);
  u = (u + 0x7fffu + ((u >> 16) & 1u)) >> 16;  // RNE
  return (u16)u;
}
__device__ __forceinline__ float bf2f(u16 h) {
  return __uint_as_float(((unsigned)h) << 16);
}
__device__ __forceinline__ f32x4 mfma16(bf16x8 a, bf16x8 b, f32x4 c) {
  return __builtin_amdgcn_mfma_f32_16x16x32_bf16(a, b, c, 0, 0, 0);
}
__device__ __forceinline__ bf16x8 ld_bf8(const u16* p) {
  return __builtin_bit_cast(bf16x8, *(const uint4v*)p);
}

// ---------------------------------------------------------------------------
// Kernel 1: per-head projections q/k/v. Wq pre-scaled by 1/8 (exact in bf16).
__global__ __launch_bounds__(256) void proj_kernel(
    const float* __restrict__ q_in, const float* __restrict__ k_in,
    const float* __restrict__ v_in, const float* __restrict__ Wq,
    const float* __restrict__ Wk, const float* __restrict__ Wv,
    u16* __restrict__ qT, u16* __restrict__ kT, u16* __restrict__ vv)
{
  const int which = blockIdx.z;
  const int bh = blockIdx.y;
  const int b = bh >> 4, h = bh & 15;
  const int s0 = blockIdx.x * 256;
  const int tid = threadIdx.x;
  const int w = tid >> 6, l = tid & 63, lr = l & 15, lg = l >> 4;

  const float* x = (which == 0) ? q_in : (which == 1) ? k_in : v_in;
  const float* W = ((which == 0) ? Wq : (which == 1) ? Wk : Wv) + h * 4096;
  const float wsc = (which == 0) ? 0.125f : 1.0f;  // fold 1/sqrt(HD) into Wq

  __shared__ alignas(16) u16 xT[256][72];
  __shared__ alignas(16) u16 Wl[64][72];

  #pragma unroll
  for (int j = 0; j < 4; ++j) {
    int i = tid * 4 + j;
    int d = i >> 4;
    int e0 = (i & 15) * 4;
    float4 f = *(const float4*)(W + d * 64 + e0);
    uint2v p;
    p[0] = (unsigned)f2bf(f.x * wsc) | ((unsigned)f2bf(f.y * wsc) << 16);
    p[1] = (unsigned)f2bf(f.z * wsc) | ((unsigned)f2bf(f.w * wsc) << 16);
    *(uint2v*)&Wl[d][e0] = p;
  }
  {
    const float* xp = x + ((size_t)b * NE + h * 64) * NS + s0 + tid;
    #pragma unroll
    for (int j = 0; j < 8; ++j) {
      uint4v pk;
      #pragma unroll
      for (int q = 0; q < 4; ++q) {
        float f0 = xp[(size_t)(j * 8 + q * 2) * NS];
        float f1 = xp[(size_t)(j * 8 + q * 2 + 1) * NS];
        pk[q] = (unsigned)f2bf(f0) | ((unsigned)f2bf(f1) << 16);
      }
      *(uint4v*)&xT[tid][j * 8] = pk;
    }
  }
  __syncthreads();

  bf16x8 af[4][2];
  #pragma unroll
  for (int mt = 0; mt < 4; ++mt) {
    af[mt][0] = ld_bf8(&Wl[mt * 16 + lr][lg * 8]);
    af[mt][1] = ld_bf8(&Wl[mt * 16 + lr][32 + lg * 8]);
  }
  f32x4 acc[4][4] = {};
  #pragma unroll
  for (int nt = 0; nt < 4; ++nt) {
    bf16x8 b0 = ld_bf8(&xT[w * 64 + nt * 16 + lr][lg * 8]);
    bf16x8 b1 = ld_bf8(&xT[w * 64 + nt * 16 + lr][32 + lg * 8]);
    #pragma unroll
    for (int mt = 0; mt < 4; ++mt) {
      acc[mt][nt] = mfma16(af[mt][0], b0, acc[mt][nt]);
      acc[mt][nt] = mfma16(af[mt][1], b1, acc[mt][nt]);
    }
  }

  if (which < 2) {
    u16* o = ((which == 0) ? qT : kT) + (size_t)bh * NS * 64;
    #pragma unroll
    for (int mt = 0; mt < 4; ++mt)
      #pragma unroll
      for (int nt = 0; nt < 4; ++nt) {
        int s = s0 + w * 64 + nt * 16 + lr;
        int d = mt * 16 + lg * 4;
        uint2v p;
        p[0] = (unsigned)f2bf(acc[mt][nt][0]) | ((unsigned)f2bf(acc[mt][nt][1]) << 16);
        p[1] = (unsigned)f2bf(acc[mt][nt][2]) | ((unsigned)f2bf(acc[mt][nt][3]) << 16);
        *(uint2v*)(o + (size_t)s * 64 + d) = p;
      }
  } else {
    u16* o = vv + (size_t)bh * 64 * NS;
    #pragma unroll
    for (int mt = 0; mt < 4; ++mt)
      #pragma unroll
      for (int nt = 0; nt < 4; ++nt)
        #pragma unroll
        for (int jr = 0; jr < 4; ++jr) {
          int d = mt * 16 + lg * 4 + jr;
          int s = s0 + w * 64 + nt * 16 + lr;
          o[(size_t)d * NS + s] = f2bf(acc[mt][nt][jr]);
        }
  }
}

// ---------------------------------------------------------------------------
// Kernel 2: Wf fp32 -> bf16
__global__ __launch_bounds__(256) void wfconv(const float* __restrict__ Wf,
                                              u16* __restrict__ Wf16) {
  int i = blockIdx.x * 256 + threadIdx.x;
  float4 f = ((const float4*)Wf)[i];
  uint2v p;
  p[0] = (unsigned)f2bf(f.x) | ((unsigned)f2bf(f.y) << 16);
  p[1] = (unsigned)f2bf(f.z) | ((unsigned)f2bf(f.w) << 16);
  ((uint2v*)Wf16)[i] = p;
}

// ---------------------------------------------------------------------------
// Kernel 3: denom. Swapped QK (A=K m=key, B=Q n=query): lane owns query lr,
// partial rowsum in-lane, reduce over lg via shfl. Then fold 1/D into v cols.
// grid 1024 = 16 row-tiles x 64 bh, heavy-first.
__global__ __launch_bounds__(256) void denom_kernel(
    const u16* __restrict__ qT, const u16* __restrict__ kT,
    u16* __restrict__ vv)
{
  const int wg = blockIdx.x;
  const int rt = 15 - (wg >> 6);
  const int bh = wg & 63;
  const int i0 = rt * 64;
  const int tid = threadIdx.x, w = tid >> 6, l = tid & 63, lr = l & 15, lg = l >> 4;
  __shared__ alignas(16) u16 klds[128][72];
  __shared__ float Dsh[64];
  const u16* qb = qT + (size_t)bh * NS * 64;
  const u16* kb = kT + (size_t)bh * NS * 64;
  const int ib = i0 + w * 16;
  const int gi = ib + lr;
  bf16x8 bq0 = ld_bf8(qb + (size_t)gi * 64 + lg * 8);
  bf16x8 bq1 = ld_bf8(qb + (size_t)gi * 64 + 32 + lg * 8);
  float den = 0.f;
  const int nkt = (rt + 2) >> 1;
  uint4v kreg[4];
  const int krow = tid >> 3, kcx = tid & 7;  // with +32 row steps per j
  #pragma unroll
  for (int j = 0; j < 4; ++j)
    kreg[j] = *(const uint4v*)(kb + (size_t)(krow + j * 32) * 64 + kcx * 8);
  for (int t = 0; t < nkt; ++t) {
    __syncthreads();
    #pragma unroll
    for (int j = 0; j < 4; ++j)
      *(uint4v*)&klds[krow + j * 32][kcx * 8] = kreg[j];
    __syncthreads();
    const int t0 = t * 128;
    if (t + 1 < nkt) {
      #pragma unroll
      for (int j = 0; j < 4; ++j)
        kreg[j] = *(const uint4v*)(kb + (size_t)(t0 + 128 + krow + j * 32) * 64 + kcx * 8);
    }
    #pragma unroll
    for (int mt = 0; mt < 8; ++mt) {
      bf16x8 a0 = ld_bf8(&klds[mt * 16 + lr][lg * 8]);
      bf16x8 a1 = ld_bf8(&klds[mt * 16 + lr][32 + lg * 8]);
      f32x4 z = {0.f, 0.f, 0.f, 0.f};
      f32x4 sc = mfma16(a0, bq0, z);
      sc = mfma16(a1, bq1, sc);
      #pragma unroll
      for (int r = 0; r < 4; ++r) {
        int gt = t0 + mt * 16 + lg * 4 + r;
        den += (gt <= gi) ? __expf(sc[r]) : 0.f;
      }
    }
  }
  den += __shfl_xor(den, 16);
  den += __shfl_xor(den, 32);
  if (l < 16) Dsh[w * 16 + lr] = den;
  __syncthreads();
  float rD = 1.0f / Dsh[l];
  u16* vp = vv + (size_t)bh * 64 * NS + i0 + l;
  #pragma unroll
  for (int d = 0; d < 16; ++d) {
    size_t off = (size_t)(d * 4 + w) * NS;
    vp[off] = f2bf(bf2f(vp[off]) * rD);
  }
}

// ---------------------------------------------------------------------------
// Kernel 4: attention. Swapped QK -> packed b64 P writes; KBLK=128; prefetch.
__global__ __launch_bounds__(256) void attn_kernel(
    const u16* __restrict__ qT, const u16* __restrict__ kT,
    const u16* __restrict__ vv, u16* __restrict__ X)
{
  const int wg = blockIdx.x;
  const int rt = 15 - (wg >> 6);
  const int bh = wg & 63;
  const int b = bh >> 4, h = bh & 15;
  const int i0 = rt * 64;
  const int tid = threadIdx.x, w = tid >> 6, l = tid & 63, lr = l & 15, lg = l >> 4;
  __shared__ alignas(16) u16 klds[128][72];   // [key][d]
  __shared__ alignas(16) u16 vlds[64][136];   // [d][j]
  __shared__ alignas(16) u16 plds[4][16][136];// per-wave [i][j]
  const u16* qb = qT + (size_t)bh * NS * 64;
  const u16* kb = kT + (size_t)bh * NS * 64;
  const u16* vb = vv + (size_t)bh * 64 * NS;
  const int ib = i0 + w * 16;
  const int gi = ib + lr;
  bf16x8 bq0 = ld_bf8(qb + (size_t)gi * 64 + lg * 8);
  bf16x8 bq1 = ld_bf8(qb + (size_t)gi * 64 + 32 + lg * 8);
  f32x4 acc[4] = {};
  const int nkt = (rt + 2) >> 1;
  uint4v kreg[4], vreg[4];
  const int krow = tid >> 3, kcx = tid & 7;
  const int vrow = tid >> 4, vcx = tid & 15;
  #pragma unroll
  for (int j = 0; j < 4; ++j) {
    kreg[j] = *(const uint4v*)(kb + (size_t)(krow + j * 32) * 64 + kcx * 8);
    vreg[j] = *(const uint4v*)(vb + (size_t)(vrow + j * 16) * NS + vcx * 8);
  }
  for (int t = 0; t < nkt; ++t) {
    __syncthreads();
    #pragma unroll
    for (int j = 0; j < 4; ++j) {
      *(uint4v*)&klds[krow + j * 32][kcx * 8] = kreg[j];
      *(uint4v*)&vlds[vrow + j * 16][vcx * 8] = vreg[j];
    }
    __syncthreads();
    const int t0 = t * 128;
    if (t + 1 < nkt) {
      const int t0n = t0 + 128;
      #pragma unroll
      for (int j = 0; j < 4; ++j) {
        kreg[j] = *(const uint4v*)(kb + (size_t)(t0n + krow + j * 32) * 64 + kcx * 8);
        vreg[j] = *(const uint4v*)(vb + (size_t)(vrow + j * 16) * NS + t0n + vcx * 8);
      }
    }
    // QK^T swapped: A=K (m=key), B=Q (n=query). exp+mask -> packed b64 P write.
    #pragma unroll
    for (int mt = 0; mt < 8; ++mt) {
      bf16x8 a0 = ld_bf8(&klds[mt * 16 + lr][lg * 8]);
      bf16x8 a1 = ld_bf8(&klds[mt * 16 + lr][32 + lg * 8]);
      f32x4 z = {0.f, 0.f, 0.f, 0.f};
      f32x4 sc = mfma16(a0, bq0, z);
      sc = mfma16(a1, bq1, sc);
      float ev[4];
      #pragma unroll
      for (int r = 0; r < 4; ++r) {
        int gt = t0 + mt * 16 + lg * 4 + r;
        ev[r] = (gt <= gi) ? __expf(sc[r]) : 0.f;
      }
      uint2v p;
      p[0] = (unsigned)f2bf(ev[0]) | ((unsigned)f2bf(ev[1]) << 16);
      p[1] = (unsigned)f2bf(ev[2]) | ((unsigned)f2bf(ev[3]) << 16);
      *(uint2v*)&plds[w][lr][mt * 16 + lg * 4] = p;  // row i=lr, 4 consecutive j
    }
    // PV: A = P (m=i, k=j), B = v' (k=j, n=d)
    bf16x8 ap[4];
    #pragma unroll
    for (int ks = 0; ks < 4; ++ks)
      ap[ks] = ld_bf8(&plds[w][lr][ks * 32 + lg * 8]);
    #pragma unroll
    for (int nt = 0; nt < 4; ++nt) {
      #pragma unroll
      for (int ks = 0; ks < 4; ++ks) {
        bf16x8 bv = ld_bf8(&vlds[nt * 16 + lr][ks * 32 + lg * 8]);
        acc[nt] = mfma16(ap[ks], bv, acc[nt]);
      }
    }
  }
  u16* Xp = X + (size_t)b * NS * NE + h * 64;
  #pragma unroll
  for (int nt = 0; nt < 4; ++nt)
    #pragma unroll
    for (int jr = 0; jr < 4; ++jr) {
      int s = ib + lg * 4 + jr;
      Xp[(size_t)s * NE + nt * 16 + lr] = f2bf(acc[nt][jr]);
    }
}

// ---------------------------------------------------------------------------
// Kernel 5: out[b][e][s] = sum_f Wf[e][f] * X[b][s][f]. 128x128 tile, 8 waves
// (each 64x32), BK=64, reg-prefetch double buffer, fp32 output.
__global__ __launch_bounds__(512) void final_gemm(
    const u16* __restrict__ Wf16, const u16* __restrict__ X,
    float* __restrict__ out)
{
  const int b = blockIdx.z;
  const int e0 = blockIdx.y * 128;
  const int s0 = blockIdx.x * 128;
  const int tid = threadIdx.x, w = tid >> 6, l = tid & 63, lr = l & 15, lg = l >> 4;
  const int wm = (w >> 2) * 64, wn = (w & 3) * 32;
  __shared__ alignas(16) u16 Alds[128][72];
  __shared__ alignas(16) u16 Blds[128][72];
  const u16* Xb = X + (size_t)b * NS * NE;
  f32x4 acc[4][2] = {};
  uint4v areg[2], breg[2];
  const int row = tid >> 3, cx = tid & 7;  // 512 threads -> rows 0..63 (+64 per j)
  #pragma unroll
  for (int j = 0; j < 2; ++j) {
    areg[j] = *(const uint4v*)(Wf16 + (size_t)(e0 + row + j * 64) * NE + cx * 8);
    breg[j] = *(const uint4v*)(Xb + (size_t)(s0 + row + j * 64) * NE + cx * 8);
  }
  for (int k0 = 0; k0 < NE; k0 += 64) {
    __syncthreads();
    #pragma unroll
    for (int j = 0; j < 2; ++j) {
      *(uint4v*)&Alds[row + j * 64][cx * 8] = areg[j];
      *(uint4v*)&Blds[row + j * 64][cx * 8] = breg[j];
    }
    __syncthreads();
    if (k0 + 64 < NE) {
      #pragma unroll
      for (int j = 0; j < 2; ++j) {
        areg[j] = *(const uint4v*)(Wf16 + (size_t)(e0 + row + j * 64) * NE + k0 + 64 + cx * 8);
        breg[j] = *(const uint4v*)(Xb + (size_t)(s0 + row + j * 64) * NE + k0 + 64 + cx * 8);
      }
    }
    #pragma unroll
    for (int kk = 0; kk < 2; ++kk) {
      bf16x8 a[4], bb[2];
      #pragma unroll
      for (int mt = 0; mt < 4; ++mt)
        a[mt] = ld_bf8(&Alds[wm + mt * 16 + lr][kk * 32 + lg * 8]);
      #pragma unroll
      for (int nt = 0; nt < 2; ++nt)
        bb[nt] = ld_bf8(&Blds[wn + nt * 16 + lr][kk * 32 + lg * 8]);
      #pragma unroll
      for (int mt = 0; mt < 4; ++mt)
        #pragma unroll
        for (int nt = 0; nt < 2; ++nt)
          acc[mt][nt] = mfma16(a[mt], bb[nt], acc[mt][nt]);
    }
  }
  #pragma unroll
  for (int mt = 0; mt < 4; ++mt)
    #pragma unroll
    for (int nt = 0; nt < 2; ++nt) {
      int e = e0 + wm + mt * 16 + lg * 4;
      int s = s0 + wn + nt * 16 + lr;
      float* op = out + ((size_t)b * NE + e) * NS + s;
      op[0] = acc[mt][nt][0];
      op[NS] = acc[mt][nt][1];
      op[2 * NS] = acc[mt][nt][2];
      op[3 * NS] = acc[mt][nt][3];
    }
}

// ---------------------------------------------------------------------------
extern "C" void kernel_launch(void* const* d_in, const int* in_sizes, int n_in,
                              void* d_out, int out_size, void* d_ws, size_t ws_size,
                              hipStream_t stream) {
  (void)in_sizes; (void)n_in; (void)out_size; (void)ws_size;
  const float* q_in = (const float*)d_in[0];
  const float* k_in = (const float*)d_in[1];
  const float* v_in = (const float*)d_in[2];
  // d_in[3] = mask: deterministic causal tril, implemented analytically
  const float* Wq = (const float*)d_in[4];
  const float* Wk = (const float*)d_in[5];
  const float* Wv = (const float*)d_in[6];
  const float* Wf = (const float*)d_in[7];

  u16* qT = (u16*)d_ws;                              // [bh][s][d]   8 MiB
  u16* kT = qT + (size_t)NB * NH * NS * HDIM;        // [bh][s][d]   8 MiB
  u16* vv = kT + (size_t)NB * NH * NS * HDIM;        // [bh][d][s]   8 MiB
  u16* X  = vv + (size_t)NB * NH * HDIM * NS;        // [b][s][f]    8 MiB
  u16* Wf16 = X + (size_t)NB * NS * NE;              // [e][f]       2 MiB

  proj_kernel<<<dim3(4, 64, 3), 256, 0, stream>>>(q_in, k_in, v_in, Wq, Wk, Wv, qT, kT, vv);
  wfconv<<<dim3(1024), 256, 0, stream>>>(Wf, Wf16);
  denom_kernel<<<dim3(1024), 256, 0, stream>>>(qT, kT, vv);
  attn_kernel<<<dim3(1024), 256, 0, stream>>>(qT, kT, vv, X);
  final_gemm<<<dim3(8, 8, 4), 512, 0, stream>>>(Wf16, X, (float*)d_out);
}